// Round 2
// baseline (14533.051 us; speedup 1.0000x reference)
//
#include <hip/hip_runtime.h>
#include <hip/hip_bf16.h>

// SignalDecoder: 2-layer bidirectional LSTM, 52 steps, B=1024, HID=256.
// Round 2: same 64-block batch-partitioned persistent kernel, but:
//  - __launch_bounds__(1024,4) -> 128 VGPR budget (R1 was capped at 64 -> serial loads)
//  - depth-3 register pipeline on weight-fragment loads (12 x 16B in flight per wave)
//  - y staged through fp32 LDS, written to `out` coalesced (float4) -> kills 4x write amp
// R1 counters: MfmaUtil 0.95%, VALUBusy 1.2%, VGPR=64 -> latency-serialized weight stream.

#define NSTEPS 52
#define LSTRIDE 520   // 512 + 8 bf16 pad

typedef __attribute__((ext_vector_type(8))) short bf16x8;
typedef __attribute__((ext_vector_type(4))) float f32x4;
typedef __attribute__((ext_vector_type(4))) unsigned int u32x4;

__device__ __forceinline__ unsigned short f2bf(float f) {
  union { float f; unsigned int u; } v; v.f = f;
  unsigned int r = v.u + 0x7fffu + ((v.u >> 16) & 1u);  // RNE
  return (unsigned short)(r >> 16);
}

// Pack weights: cell c (0=l0f,1=l0b,2=l1f,3=l1b), Wcat = [W_ih (K=512) | W_hh (K=256)],
// chunk (c, n16, kc): lane l holds W[n16*16 + (l&15)][kc*32 + (l>>4)*8 + j], j=0..7.
// chunk short-offset = ((c*64 + n16)*24 + kc)*512 + lane*8. bsum[c*1024+n] = b_ih+b_hh.
__global__ void wpack_kernel(const float* __restrict__ Wih0, const float* __restrict__ Whh0,
                             const float* __restrict__ bih0, const float* __restrict__ bhh0,
                             const float* __restrict__ Wih1, const float* __restrict__ Whh1,
                             const float* __restrict__ bih1, const float* __restrict__ bhh1,
                             unsigned short* __restrict__ wpack, float* __restrict__ bsum) {
  int tid = blockIdx.x * 256 + threadIdx.x;  // 4*64*24*64 = 393216 threads
  int lane = tid & 63;
  int chunk = tid >> 6;
  int kc = chunk % 24;
  int cn = chunk / 24;
  int n16 = cn & 63;
  int c = cn >> 6;
  int n = n16 * 16 + (lane & 15);
  int k0 = kc * 32 + (lane >> 4) * 8;
  const float* Wih = (c < 2) ? Wih0 : Wih1;
  const float* Whh = (c < 2) ? Whh0 : Whh1;
  int d = c & 1;
  unsigned short tmp[8];
#pragma unroll
  for (int j = 0; j < 8; j++) {
    int k = k0 + j;
    float val = (k < 512) ? Wih[(d * 1024 + n) * 512 + k]
                          : Whh[(d * 1024 + n) * 256 + (k - 512)];
    tmp[j] = f2bf(val);
  }
  *(u32x4*)(wpack + (size_t)tid * 8) = *(const u32x4*)tmp;
  if (tid < 4096) {
    int c2 = tid >> 10, n2 = tid & 1023;
    float b = (c2 < 2) ? (bih0[(c2 & 1) * 1024 + n2] + bhh0[(c2 & 1) * 1024 + n2])
                       : (bih1[(c2 & 1) * 1024 + n2] + bhh1[(c2 & 1) * 1024 + n2]);
    bsum[tid] = b;
  }
}

__device__ __forceinline__ float sigm(float x) { return 1.f / (1.f + __expf(-x)); }
__device__ __forceinline__ float tanh_f(float x) { return 2.f / (1.f + __expf(-2.f * x)) - 1.f; }

// One gate-group GEMM: [16 batch x 64 gate-cols (4 gates x 16)] over K = kc in [KC0,24).
// wbt already includes cell base + tt offset + lane*8. Depth-3 register pipeline.
template <int KC0>
__device__ __forceinline__ void gate_mm(const unsigned short* __restrict__ Xsrc,
                                        const unsigned short* __restrict__ Hsrc,
                                        const unsigned short* __restrict__ wbt,
                                        int axo, f32x4 (&acc)[4]) {
  constexpr int N = 24 - KC0;
  bf16x8 Br[3][4];
#pragma unroll
  for (int pf = 0; pf < 2; pf++) {
    const unsigned short* p = wbt + (KC0 + pf) * 512;
#pragma unroll
    for (int g = 0; g < 4; g++) Br[pf][g] = *(const bf16x8*)(p + g * 196608);
  }
#pragma unroll
  for (int i = 0; i < N; i++) {
    const int kc = KC0 + i;
    const int cur = i % 3;
    if (i + 2 < N) {
      const int nb = (i + 2) % 3;
      const unsigned short* p = wbt + (kc + 2) * 512;
#pragma unroll
      for (int g = 0; g < 4; g++) Br[nb][g] = *(const bf16x8*)(p + g * 196608);
    }
    const unsigned short* ap = (kc < 16) ? (Xsrc + kc * 32) : (Hsrc + (kc - 16) * 32);
    bf16x8 af = *(const bf16x8*)(ap + axo);
#pragma unroll
    for (int g = 0; g < 4; g++)
      acc[g] = __builtin_amdgcn_mfma_f32_16x16x32_bf16(af, Br[cur][g], acc[g], 0, 0, 0);
  }
}

__global__ __launch_bounds__(1024, 4) void lstm_kernel(
    const float* __restrict__ code,
    const unsigned short* __restrict__ wpack,
    const float* __restrict__ bsum,
    float* __restrict__ out) {
  __shared__ unsigned short Xbuf[16 * LSTRIDE];  // [h0f | h0b]
  __shared__ unsigned short Ybuf[16 * LSTRIDE];  // [h1f | h1b] == y
  __shared__ float Ostage[16 * 512];             // fp32 y staging for coalesced out

  const int tid = threadIdx.x;
  const int lane = tid & 63;
  const int w = tid >> 6;        // wave 0..15
  const int half = w >> 3;       // fwd/bwd cell within stage
  const int hs = w & 7;          // 32-wide hidden slice
  const int rowbase = blockIdx.x * 16;
  const int lrow = (lane >> 4) * 4;            // + r -> MFMA D row
  const int lcol = hs * 32 + (lane & 15);      // + tt*16 -> hidden index

  // init LDS from code: h0 cells 0,1 -> Xbuf; cells 2,3 -> Ybuf
  for (int idx = tid; idx < 16 * 1024; idx += 1024) {
    int row = idx >> 10, col = idx & 1023;
    int cs = col >> 8, hid = col & 255;
    unsigned short b = f2bf(code[(rowbase + row) * 2048 + cs * 256 + hid]);
    if (cs < 2) Xbuf[row * LSTRIDE + col] = b;
    else        Ybuf[row * LSTRIDE + (col - 512)] = b;
  }

  // c0 + bias sums into registers; [stage][tt][...]
  float creg[2][2][4];
  float brg[2][2][4];
#pragma unroll
  for (int s = 0; s < 2; s++) {
    int cell = s * 2 + half;
#pragma unroll
    for (int tt = 0; tt < 2; tt++) {
      int colh = lcol + tt * 16;
#pragma unroll
      for (int r = 0; r < 4; r++)
        creg[s][tt][r] = code[(rowbase + lrow + r) * 2048 + 1024 + cell * 256 + colh];
#pragma unroll
      for (int g = 0; g < 4; g++)
        brg[s][tt][g] = bsum[cell * 1024 + g * 256 + colh];
    }
  }
  __syncthreads();

  const int axo = (lane & 15) * LSTRIDE + (lane >> 4) * 8;

  for (int step = 0; step < NSTEPS; step++) {
#pragma unroll
    for (int s = 0; s < 2; s++) {
      const unsigned short* __restrict__ Xsrc = (s == 0) ? Ybuf : Xbuf;                // k<512
      const unsigned short* __restrict__ Hsrc = ((s == 0) ? Xbuf : Ybuf) + half * 256; // k>=512
      unsigned short* __restrict__ Dst = (s == 0) ? Xbuf : Ybuf;
      const int cell = s * 2 + half;
      float hval[2][4];

#pragma unroll
      for (int tt = 0; tt < 2; tt++) {
        const unsigned short* __restrict__ wbt =
            wpack + (size_t)cell * 786432 + (size_t)(hs * 2 + tt) * 12288 + (size_t)lane * 8;
        f32x4 acc[4];
#pragma unroll
        for (int g = 0; g < 4; g++) acc[g] = (f32x4){0.f, 0.f, 0.f, 0.f};

        if (step == 0 && s == 0) gate_mm<16>(Xsrc, Hsrc, wbt, axo, acc);  // y_0 == 0
        else                     gate_mm<0>(Xsrc, Hsrc, wbt, axo, acc);

#pragma unroll
        for (int r = 0; r < 4; r++) {
          float iv = sigm(acc[0][r] + brg[s][tt][0]);
          float fv = sigm(acc[1][r] + brg[s][tt][1]);
          float gv = tanh_f(acc[2][r] + brg[s][tt][2]);
          float ov = sigm(acc[3][r] + brg[s][tt][3]);
          float c2 = fv * creg[s][tt][r] + iv * gv;
          creg[s][tt][r] = c2;
          float hv = ov * tanh_f(c2);
          hval[tt][r] = hv;
          if (s == 1)  // stage y in fp32 for coalesced global write
            Ostage[(lrow + r) * 512 + half * 256 + lcol + tt * 16] = hv;
        }
      }

      __syncthreads();  // all reads of Dst (h-state) done before overwrite
#pragma unroll
      for (int tt = 0; tt < 2; tt++)
#pragma unroll
        for (int r = 0; r < 4; r++)
          Dst[(lrow + r) * LSTRIDE + half * 256 + lcol + tt * 16] = f2bf(hval[tt][r]);
      __syncthreads();

      if (s == 1) {  // coalesced y write: 16 rows x 512 fp32, float4 per lane x2
        int orow = tid >> 6, oc = (tid & 63) * 4;
        float4 va = *(const float4*)&Ostage[orow * 512 + oc];
        float4 vb = *(const float4*)&Ostage[orow * 512 + 256 + oc];
        size_t ob = ((size_t)(rowbase + orow) * NSTEPS + step) * 512;
        *(float4*)(out + ob + oc) = va;
        *(float4*)(out + ob + 256 + oc) = vb;
      }
    }
  }
}

extern "C" void kernel_launch(void* const* d_in, const int* in_sizes, int n_in,
                              void* d_out, int out_size, void* d_ws, size_t ws_size,
                              hipStream_t stream) {
  const float* code = (const float*)d_in[0];
  // d_in[1] = x  -- unused by the reference
  const float* Wih0 = (const float*)d_in[2];
  const float* Whh0 = (const float*)d_in[3];
  const float* bih0 = (const float*)d_in[4];
  const float* bhh0 = (const float*)d_in[5];
  const float* Wih1 = (const float*)d_in[6];
  const float* Whh1 = (const float*)d_in[7];
  const float* bih1 = (const float*)d_in[8];
  const float* bhh1 = (const float*)d_in[9];

  unsigned short* wpack = (unsigned short*)d_ws;                  // 6,291,456 B
  float* bsum = (float*)((char*)d_ws + 6291456);                  // 16 KB

  wpack_kernel<<<1536, 256, 0, stream>>>(Wih0, Whh0, bih0, bhh0,
                                         Wih1, Whh1, bih1, bhh1, wpack, bsum);
  lstm_kernel<<<64, 1024, 0, stream>>>(code, wpack, bsum, (float*)d_out);
}

// Round 3
// 1543.853 us; speedup vs baseline: 9.4135x; 9.4135x over previous
//
#include <hip/hip_runtime.h>
#include <hip/hip_bf16.h>

// SignalDecoder: 2-layer bidirectional LSTM, 52 steps, B=1024, HID=256.
// Round 3: one kernel per LSTM stage (104 total) — kernel boundary is the sync.
//   R1/R2 lesson: 64-block weight-streaming kernel is latency-serialized (MfmaUtil
//   0.94%, ~23 GB/s/CU weight stream); compiler defeats source-level pipelining.
//   New: 256 blocks/stage (2 cells x 16 hid-slices x 8 M-tiles of 128 rows), 512 thr.
//   Weights (96KB/block, MFMA-fragment order) DMA'd to LDS via global_load_lds w=16;
//   A-frags (24 x 16B/lane) in registers; 96 MFMA/wave; in-register epilogue (all 4
//   gates of a hidden element land in the same lane: gates are separate N-tiles with
//   the same column). h ping-pongs between 2 global slots by step parity; c fp32 in ws.

#define NSTEPS 52

typedef __attribute__((ext_vector_type(8))) short bf16x8;
typedef __attribute__((ext_vector_type(4))) float f32x4;
typedef __attribute__((ext_vector_type(4))) unsigned int u32x4;

__device__ __forceinline__ unsigned short f2bf(float f) {
  union { float f; unsigned int u; } v; v.f = f;
  unsigned int r = v.u + 0x7fffu + ((v.u >> 16) & 1u);  // RNE
  return (unsigned short)(r >> 16);
}

__device__ __forceinline__ float sigm(float x) { return 1.f / (1.f + __expf(-x)); }
__device__ __forceinline__ float tanh_f(float x) { return 2.f / (1.f + __expf(-2.f * x)) - 1.f; }

__device__ __forceinline__ void async_ld16(const unsigned short* g, unsigned short* l) {
  __builtin_amdgcn_global_load_lds(
      (const __attribute__((address_space(1))) unsigned int*)g,
      (__attribute__((address_space(3))) unsigned int*)l, 16, 0, 0);
}

// Pack weights: cell c (0=l0f,1=l0b,2=l1f,3=l1b), Wcat = [W_ih (K=512) | W_hh (K=256)],
// chunk (c, n16, kc): lane l holds W[n16*16 + (l&15)][kc*32 + (l>>4)*8 + j], j=0..7.
// chunk short-offset = ((c*64 + n16)*24 + kc)*512 + lane*8. n16 = gate*16 + hsl.
// bsum[c*1024+n] = b_ih+b_hh.
__global__ void wpack_kernel(const float* __restrict__ Wih0, const float* __restrict__ Whh0,
                             const float* __restrict__ bih0, const float* __restrict__ bhh0,
                             const float* __restrict__ Wih1, const float* __restrict__ Whh1,
                             const float* __restrict__ bih1, const float* __restrict__ bhh1,
                             unsigned short* __restrict__ wpack, float* __restrict__ bsum) {
  int tid = blockIdx.x * 256 + threadIdx.x;  // 4*64*24*64 = 393216 threads
  int lane = tid & 63;
  int chunk = tid >> 6;
  int kc = chunk % 24;
  int cn = chunk / 24;
  int n16 = cn & 63;
  int c = cn >> 6;
  int n = n16 * 16 + (lane & 15);
  int k0 = kc * 32 + (lane >> 4) * 8;
  const float* Wih = (c < 2) ? Wih0 : Wih1;
  const float* Whh = (c < 2) ? Whh0 : Whh1;
  int d = c & 1;
  unsigned short tmp[8];
#pragma unroll
  for (int j = 0; j < 8; j++) {
    int k = k0 + j;
    float val = (k < 512) ? Wih[(d * 1024 + n) * 512 + k]
                          : Whh[(d * 1024 + n) * 256 + (k - 512)];
    tmp[j] = f2bf(val);
  }
  *(u32x4*)(wpack + (size_t)tid * 8) = *(const u32x4*)tmp;
  if (tid < 4096) {
    int c2 = tid >> 10, n2 = tid & 1023;
    float b = (c2 < 2) ? (bih0[(c2 & 1) * 1024 + n2] + bhh0[(c2 & 1) * 1024 + n2])
                       : (bih1[(c2 & 1) * 1024 + n2] + bhh1[(c2 & 1) * 1024 + n2]);
    bsum[tid] = b;
  }
}

// init: h0 -> H slot 1 ([row][cell*256+hid] bf16), c0 -> C ([row][cell*256+hid] fp32)
__global__ void init_kernel(const float* __restrict__ code,
                            unsigned short* __restrict__ H1, float* __restrict__ C) {
  int t = blockIdx.x * 256 + threadIdx.x;  // 1M threads
  int row = t >> 10, col = t & 1023;
  H1[t] = f2bf(code[row * 2048 + col]);
  C[t] = code[row * 2048 + 1024 + col];
}

// One LSTM stage: gates = A[1024 x 768] * Wcat^T for 2 cells, fused LSTM epilogue.
// Block = (cell01, hsl in 0..15 -> 16 hidden, mb in 0..7 -> 128 rows). 512 threads.
// A(row,k): k<512 -> Xb[row*1024+k]; k>=512 -> Hp[row*1024 + cell*256 + k-512].
template <int KC0>
__device__ __forceinline__ void stage_body(
    const unsigned short* __restrict__ Xb, const unsigned short* __restrict__ Hp,
    unsigned short* __restrict__ Hw, float* __restrict__ C,
    const float* __restrict__ bsum, const unsigned short* __restrict__ wpack,
    float* __restrict__ out, int cell0, int step,
    unsigned short* Blds) {
  const int bx = blockIdx.x;
  const int mb = bx & 7;
  const int hsl = (bx >> 3) & 15;
  const int cell = cell0 + (bx >> 7);
  const int tid = threadIdx.x;
  const int lane = tid & 63;
  const int w = tid >> 6;          // wave id = M-tile within the 128-row block
  const int q = lane >> 4;
  const int ln = lane & 15;

  // --- B staging: 96 fragment chunks (4 gates x 24 kc), 1KB each, async DMA to LDS.
  // Blds layout: [kc][gate][512 shorts]; chunk ci = kc*4 + gate.
#pragma unroll
  for (int i = 0; i < 12; i++) {
    int ci = w + i * 8;
    int gate = ci & 3, kc = ci >> 2;
    if (kc >= KC0) {
      const unsigned short* gp =
          wpack + ((size_t)((cell * 64 + gate * 16 + hsl) * 24 + kc)) * 512 + lane * 8;
      async_ld16(gp, Blds + (size_t)ci * 512);
    }
  }

  // --- A fragments to registers: 24-KC0 x 16B per lane.
  const int arow = (mb * 128 + w * 16 + ln) * 1024 + q * 8;
  bf16x8 afr[24];
#pragma unroll
  for (int kc = KC0; kc < 24; kc++) {
    const unsigned short* ap = (kc < 16) ? (Xb + arow + kc * 32)
                                         : (Hp + arow + cell * 256 + (kc - 16) * 32);
    afr[kc] = *(const bf16x8*)ap;
  }

  f32x4 acc[4];
#pragma unroll
  for (int g = 0; g < 4; g++) acc[g] = (f32x4){0.f, 0.f, 0.f, 0.f};

  __syncthreads();  // drains vmcnt: B in LDS, A in regs

#pragma unroll
  for (int kc = KC0; kc < 24; kc++) {
#pragma unroll
    for (int g = 0; g < 4; g++) {
      bf16x8 bf = *(const bf16x8*)(Blds + (size_t)(kc * 4 + g) * 512 + lane * 8);
      acc[g] = __builtin_amdgcn_mfma_f32_16x16x32_bf16(afr[kc], bf, acc[g], 0, 0, 0);
    }
  }

  // --- epilogue: lane holds gates i,f,g,o for (rows q*4+r, hidden colh)
  const int colh = hsl * 16 + ln;
  float brg[4];
#pragma unroll
  for (int g = 0; g < 4; g++) brg[g] = bsum[cell * 1024 + g * 256 + colh];

#pragma unroll
  for (int r = 0; r < 4; r++) {
    int row = mb * 128 + w * 16 + q * 4 + r;
    size_t cidx = (size_t)row * 1024 + cell * 256 + colh;
    float cp = C[cidx];
    float iv = sigm(acc[0][r] + brg[0]);
    float fv = sigm(acc[1][r] + brg[1]);
    float gv = tanh_f(acc[2][r] + brg[2]);
    float ov = sigm(acc[3][r] + brg[3]);
    float c2 = fv * cp + iv * gv;
    C[cidx] = c2;
    float hv = ov * tanh_f(c2);
    Hw[cidx] = f2bf(hv);
    if (cell0 == 2)  // layer-1 stage: y == output
      out[(size_t)row * (NSTEPS * 512) + step * 512 + (cell - 2) * 256 + colh] = hv;
  }
}

__global__ __launch_bounds__(512, 2) void stage_kernel(
    const unsigned short* __restrict__ Xb, const unsigned short* __restrict__ Hp,
    unsigned short* __restrict__ Hw, float* __restrict__ C,
    const float* __restrict__ bsum, const unsigned short* __restrict__ wpack,
    float* __restrict__ out, int cell0, int step, int kc0) {
  __shared__ unsigned short Blds[96 * 512];  // 96 KB
  if (kc0 == 16)
    stage_body<16>(Xb, Hp, Hw, C, bsum, wpack, out, cell0, step, Blds);
  else
    stage_body<0>(Xb, Hp, Hw, C, bsum, wpack, out, cell0, step, Blds);
}

extern "C" void kernel_launch(void* const* d_in, const int* in_sizes, int n_in,
                              void* d_out, int out_size, void* d_ws, size_t ws_size,
                              hipStream_t stream) {
  const float* code = (const float*)d_in[0];
  // d_in[1] = x  -- unused by the reference
  const float* Wih0 = (const float*)d_in[2];
  const float* Whh0 = (const float*)d_in[3];
  const float* bih0 = (const float*)d_in[4];
  const float* bhh0 = (const float*)d_in[5];
  const float* Wih1 = (const float*)d_in[6];
  const float* Whh1 = (const float*)d_in[7];
  const float* bih1 = (const float*)d_in[8];
  const float* bhh1 = (const float*)d_in[9];

  // d_ws layout
  unsigned short* wpack = (unsigned short*)d_ws;                        // 6,291,456 B
  float* bsum = (float*)((char*)d_ws + 6291456);                        // 16 KB
  float* C    = (float*)((char*)d_ws + 6291456 + 16384);                // 4 MB
  unsigned short* H0 = (unsigned short*)((char*)d_ws + 6291456 + 16384 + 4194304);  // 2 MB
  unsigned short* H1 = H0 + 1024 * 1024;                                // 2 MB

  float* out = (float*)d_out;

  wpack_kernel<<<1536, 256, 0, stream>>>(Wih0, Whh0, bih0, bhh0,
                                         Wih1, Whh1, bih1, bhh1, wpack, bsum);
  init_kernel<<<4096, 256, 0, stream>>>(code, H1, C);

  for (int t = 0; t < NSTEPS; t++) {
    unsigned short* Hprev = (t & 1) ? H0 : H1;  // slot (t-1)&1
    unsigned short* Hcur  = (t & 1) ? H1 : H0;  // slot t&1
    // stage 0 (layer 0): X = prev y = Hprev cells 2,3; own h = Hprev cells 0,1
    stage_kernel<<<256, 512, 0, stream>>>(Hprev + 512, Hprev, Hcur, C, bsum, wpack,
                                          out, 0, t, (t == 0) ? 16 : 0);
    // stage 1 (layer 1): X = fresh h0 = Hcur cells 0,1; own h = Hprev cells 2,3
    stage_kernel<<<256, 512, 0, stream>>>(Hcur, Hprev, Hcur, C, bsum, wpack,
                                          out, 2, t, 0);
  }
}